// Round 3
// baseline (138.840 us; speedup 1.0000x reference)
//
#include <hip/hip_runtime.h>
#include <cmath>

#define NB 16
#define NA 5
#define NH 152
#define NW 152
#define NT 50
#define NC 20
#define CH (6 + NC)     // 26 prediction channels
#define TCH (13 + NC)   // 33 target channels
#define NCELL (NB * NA * NH * NW)        // 1,848,320 cells (conf elements)
#define TOT4 (NCELL * CH / 4)            // 12,014,080 float4 in pred
#define NBLK 2048                        // stream grid

// anchors / SCALE: (16,16),(32,32),(64,64),(96,48),(48,96) / 4
__device__ __constant__ float c_aw[NA] = {4.f, 8.f, 16.f, 24.f, 12.f};
__device__ __constant__ float c_ah[NA] = {4.f, 8.f, 16.f, 12.f, 24.f};

// packed target word: bits0-7 gi | 8-15 gj | 16-20 ignore mask | 21-25 best_n one-hot | 26 valid
#define VALID_BIT (1u << 26)

__device__ __forceinline__ float bce0(float l) {  // bce(logit, target=0)
  return fmaxf(l, 0.f) + log1pf(expf(-fabsf(l)));
}

// ---------------------------------------------------------------------------
// Pure stream: sum bce(conf,0) over ALL cells. No target dependency at all.
// Per-block partial WRITTEN to ws (overwrite -> no zeroing needed).
// ---------------------------------------------------------------------------
__global__ __launch_bounds__(256) void k_stream(
    const float* __restrict__ pred, float* __restrict__ partials) {
  const float4* p4 = (const float4*)pred;
  float s = 0.f;
  const int stride = NBLK * 256;
  for (int q = blockIdx.x * 256 + threadIdx.x; q < TOT4; q += stride) {
    const float4 v = p4[q];
    // float index f0 = 4q; f0 mod 26 is even; conf present iff q%13==0 (v.x) or q%13==6 (v.z)
    const int r = q % 13;
    if (r == 0) s += bce0(v.x);
    else if (r == 6) s += bce0(v.z);
  }
  for (int off = 32; off >= 1; off >>= 1) s += __shfl_down(s, off, 64);
  __shared__ float sw[4];
  const int wave = threadIdx.x >> 6;
  if ((threadIdx.x & 63) == 0) sw[wave] = s;
  __syncthreads();
  if (threadIdx.x == 0) partials[blockIdx.x] = sw[0] + sw[1] + sw[2] + sw[3];
}

// ---------------------------------------------------------------------------
// Single-block fixup: targets, coord/class losses, obj-BCE add, noobj
// corrections for mask & ignored cells, final combine.
// ---------------------------------------------------------------------------
__global__ __launch_bounds__(1024) void k_fix(
    const float* __restrict__ pred, const float* __restrict__ tgt,
    const int* __restrict__ tsz, const float* __restrict__ partials,
    float* __restrict__ out) {
  __shared__ unsigned int s_packed[NB * NT];
  __shared__ float s_acc[10];
  // acc slots: 0..3 coord, 4 ce, 5 n_obj, 6 s_ob(bce1), 7 s_sub(bce0 removed), 8 n_excl, 9 s_all
  const int tid = threadIdx.x;
  if (tid < 10) s_acc[tid] = 0.f;

  const int b = tid / NT;
  const int t = tid - b * NT;
  unsigned int word = 0;
  int gi = 0, gj = 0, bestn = 0, label = 0;
  float txv = 0, tyv = 0, twv = 0, thv = 0;
  bool valid = false;

  if (tid < NB * NT) {
    const float* tr = tgt + (size_t)tid * TCH;
    const float gx = tr[0] * 0.25f, gy = tr[1] * 0.25f;
    const float gh = tr[3] * 0.25f, gw = tr[4] * 0.25f;
    valid = (t < tsz[b]) && (gw > 0.f) && (gh > 0.f);
    gi = min(max((int)gx, 0), NW - 1);
    gj = min(max((int)gy, 0), NH - 1);
    const float area_gt = (gw + 1.f) * (gh + 1.f);
    float best = -1.f;
    unsigned amask = 0;
    for (int a = 0; a < NA; ++a) {
      const float inter = (fminf(gw, c_aw[a]) + 1.f) * (fminf(gh, c_ah[a]) + 1.f);
      const float area_a = (c_aw[a] + 1.f) * (c_ah[a] + 1.f);
      const float iou = inter / (area_gt + area_a - inter + 1e-16f);
      if (iou > best) { best = iou; bestn = a; }   // first-max tie-break
      if (iou > 0.5f) amask |= (1u << a);
    }
    txv = atanhf(gx - ((float)gi + 0.5f));
    tyv = atanhf(gy - ((float)gj + 0.5f));
    twv = logf(gw / c_aw[bestn] + 1e-16f);
    thv = logf(gh / c_ah[bestn] + 1e-16f);
    float bc = tr[13];
    label = 0;
    for (int c = 1; c < NC; ++c)
      if (tr[13 + c] > bc) { bc = tr[13 + c]; label = c; }
    if (valid)
      word = (unsigned)gi | ((unsigned)gj << 8) | (amask << 16) |
             (1u << (21 + bestn)) | VALID_BIT;
    s_packed[tid] = word;
  }
  __syncthreads();

  // --- coord/mask winners: last-update-wins per (cell, best_n) ---
  bool winner = false;
  if (valid) {
    winner = true;
    const unsigned keymask = 0xFFFFu | (0x1Fu << 21);
    const unsigned mykey = word & keymask;
    for (int t2 = t + 1; t2 < NT; ++t2) {
      const unsigned w2 = s_packed[b * NT + t2];
      if ((w2 & VALID_BIT) && ((w2 & keymask) == mykey)) { winner = false; break; }
    }
  }

  float cx = 0, cy = 0, cw = 0, chh = 0, cce = 0, cn = 0;
  float s_ob = 0, s_sub = 0, n_excl = 0;
  if (winner) {
    const size_t cell = ((((size_t)b * NA + bestn) * NH + gj) * NW + gi) * CH;
    const float* p = pred + cell;
    const float l0 = p[0];
    const float px = p[1], py = p[2], ph = p[4], pw = p[5];
    cx = (px - txv) * (px - txv);
    cy = (py - tyv) * (py - tyv);
    cw = (pw - twv) * (pw - twv);
    chh = (ph - thv) * (ph - thv);
    float m = p[6];
    for (int c = 1; c < NC; ++c) m = fmaxf(m, p[6 + c]);
    float s = 0.f;
    for (int c = 0; c < NC; ++c) s += expf(p[6 + c] - m);
    cce = (m + logf(s)) - p[6 + label];
    cn = 1.f;
    const float b0 = bce0(l0);
    s_ob = b0 - l0;      // bce(l,1) = bce(l,0) - l
    s_sub = b0;          // remove this cell from the noobj sum
    n_excl = 1.f;
  }

  // --- ignored-not-masked cells: first-t dedupe per (cell, anchor) ---
  for (int u = tid; u < NB * NT * NA; u += 1024) {
    const int bt = u / NA;
    const int a = u - bt * NA;
    const unsigned w = s_packed[bt];
    if (!(w & VALID_BIT) || !((w >> (16 + a)) & 1u)) continue;
    const int bb = bt / NT, tt = bt - bb * NT;
    const unsigned key = w & 0xFFFFu;  // gi | gj
    bool first = true;
    for (int t2 = 0; t2 < tt; ++t2) {
      const unsigned w2 = s_packed[bb * NT + t2];
      if ((w2 & VALID_BIT) && ((w2 & 0xFFFFu) == key) && ((w2 >> (16 + a)) & 1u)) {
        first = false; break;
      }
    }
    if (!first) continue;
    bool msk = false;   // masked by ANY target at this (cell, anchor)?
    for (int t2 = 0; t2 < NT; ++t2) {
      const unsigned w2 = s_packed[bb * NT + t2];
      if ((w2 & VALID_BIT) && ((w2 & 0xFFFFu) == key) && ((w2 >> (21 + a)) & 1u)) {
        msk = true; break;
      }
    }
    if (msk) continue;  // already excluded via the winner path
    const int ii = w & 0xFFu, jj = (w >> 8) & 0xFFu;
    const float l = pred[((((size_t)bb * NA + a) * NH + jj) * NW + ii) * CH];
    s_sub += bce0(l);
    n_excl += 1.f;
  }

  // --- stream partials (2048 floats in ws) ---
  float s_all = partials[tid] + partials[tid + 1024];

  // --- block reduce 10 accumulators ---
  for (int off = 32; off >= 1; off >>= 1) {
    cx    += __shfl_down(cx, off, 64);
    cy    += __shfl_down(cy, off, 64);
    cw    += __shfl_down(cw, off, 64);
    chh   += __shfl_down(chh, off, 64);
    cce   += __shfl_down(cce, off, 64);
    cn    += __shfl_down(cn, off, 64);
    s_ob  += __shfl_down(s_ob, off, 64);
    s_sub += __shfl_down(s_sub, off, 64);
    n_excl+= __shfl_down(n_excl, off, 64);
    s_all += __shfl_down(s_all, off, 64);
  }
  if ((tid & 63) == 0) {
    atomicAdd(&s_acc[0], cx);
    atomicAdd(&s_acc[1], cy);
    atomicAdd(&s_acc[2], cw);
    atomicAdd(&s_acc[3], chh);
    atomicAdd(&s_acc[4], cce);
    atomicAdd(&s_acc[5], cn);
    atomicAdd(&s_acc[6], s_ob);
    atomicAdd(&s_acc[7], s_sub);
    atomicAdd(&s_acc[8], n_excl);
    atomicAdd(&s_acc[9], s_all);
  }
  __syncthreads();
  if (tid == 0) {
    const float n_obj = fmaxf(s_acc[5], 1.f);
    const float n_noobj = fmaxf((float)NCELL - s_acc[8], 1.f);
    out[0] = (s_acc[0] + s_acc[1] + s_acc[2] + s_acc[3] + s_acc[4] + s_acc[6]) / n_obj +
             1.25f * (s_acc[9] - s_acc[7]) / n_noobj;
  }
}

extern "C" void kernel_launch(void* const* d_in, const int* in_sizes, int n_in,
                              void* d_out, int out_size, void* d_ws, size_t ws_size,
                              hipStream_t stream) {
  const float* pred = (const float*)d_in[0];
  const float* tgt = (const float*)d_in[1];
  const int* tsz = (const int*)d_in[2];
  float* out = (float*)d_out;
  float* partials = (float*)d_ws;   // 2048 floats, fully overwritten each call

  k_stream<<<NBLK, 256, 0, stream>>>(pred, partials);
  k_fix<<<1, 1024, 0, stream>>>(pred, tgt, tsz, partials, out);
}

// Round 4
// 112.985 us; speedup vs baseline: 1.2288x; 1.2288x over previous
//
#include <hip/hip_runtime.h>
#include <cmath>

#define NB 16
#define NA 5
#define NH 152
#define NW 152
#define NT 50
#define NC 20
#define CH 26          // prediction channels
#define TCH 33         // target channels
#define NBT (NB * NT)  // 800 (b,t) pairs
#define NCELL (NB * NA * NH * NW)  // 1,848,320 conf cells
#define GBLK 1805      // gather blocks: GBLK * 1024 == NCELL exactly

// anchors / SCALE
__device__ __constant__ float c_aw[NA] = {4.f, 8.f, 16.f, 24.f, 12.f};
__device__ __constant__ float c_ah[NA] = {4.f, 8.f, 16.f, 12.f, 24.f};

// packed word: bits0-7 gi | 8-15 gj | 16-20 ignore mask | 21-25 best_n one-hot | 26 valid
#define VALID_BIT (1u << 26)

__device__ __forceinline__ float bce0(float l) {  // bce(logit, target=0)
  return fmaxf(l, 0.f) + log1pf(expf(-fabsf(l)));
}

// ws float layout: [0..16) acc  (0-3 coord, 4 ce, 5 n_obj, 6 s_ob, 7 s_sub_mask, 8 n_mask)
//                  [64..864)   packed words (800)
//                  [1024..2829) partials (1805, fully overwritten)

__global__ __launch_bounds__(256) void k_main(
    const float* __restrict__ pred, const float* __restrict__ tgt,
    const int* __restrict__ tsz, float* __restrict__ acc,
    unsigned* __restrict__ packed_out, float* __restrict__ partials) {
  if (blockIdx.x < GBLK) {
    // ---- pure conf gather: 4 independent scalar loads, zero per-cell logic ----
    const int base = blockIdx.x * 1024 + threadIdx.x;
    const float l0 = pred[(size_t)base * CH];
    const float l1 = pred[(size_t)(base + 256) * CH];
    const float l2 = pred[(size_t)(base + 512) * CH];
    const float l3 = pred[(size_t)(base + 768) * CH];
    float s = bce0(l0) + bce0(l1) + bce0(l2) + bce0(l3);
    for (int off = 32; off >= 1; off >>= 1) s += __shfl_down(s, off, 64);
    __shared__ float sw[4];
    if ((threadIdx.x & 63) == 0) sw[threadIdx.x >> 6] = s;
    __syncthreads();
    if (threadIdx.x == 0) partials[blockIdx.x] = sw[0] + sw[1] + sw[2] + sw[3];
    return;
  }

  // ---- targets block (runs concurrently with the gather blocks) ----
  __shared__ unsigned s_packed[NBT];
  __shared__ float s_acc[9];
  const int tid = threadIdx.x;
  if (tid < 9) s_acc[tid] = 0.f;

  #pragma unroll
  for (int k = 0; k < 4; ++k) {
    const int bt = tid + k * 256;
    if (bt < NBT) {
      const int b = bt / NT, t = bt - b * NT;
      const float* tr = tgt + (size_t)bt * TCH;
      const float gx = tr[0] * 0.25f, gy = tr[1] * 0.25f;
      const float gh = tr[3] * 0.25f, gw = tr[4] * 0.25f;
      const bool valid = (t < tsz[b]) && (gw > 0.f) && (gh > 0.f);
      const int gi = min(max((int)gx, 0), NW - 1);
      const int gj = min(max((int)gy, 0), NH - 1);
      const float area_gt = (gw + 1.f) * (gh + 1.f);
      float best = -1.f; int bestn = 0; unsigned amask = 0;
      for (int a = 0; a < NA; ++a) {
        const float inter = (fminf(gw, c_aw[a]) + 1.f) * (fminf(gh, c_ah[a]) + 1.f);
        const float area_a = (c_aw[a] + 1.f) * (c_ah[a] + 1.f);
        const float iou = inter / (area_gt + area_a - inter + 1e-16f);
        if (iou > best) { best = iou; bestn = a; }   // first-max tie-break
        if (iou > 0.5f) amask |= (1u << a);
      }
      unsigned word = 0;
      if (valid)
        word = (unsigned)gi | ((unsigned)gj << 8) | (amask << 16) |
               (1u << (21 + bestn)) | VALID_BIT;
      s_packed[bt] = word;
      packed_out[bt] = word;
    }
  }
  __syncthreads();

  float cx = 0, cy = 0, cw = 0, chh = 0, cce = 0, cn = 0;
  float s_ob = 0, s_sub = 0, n_msk = 0;
  #pragma unroll
  for (int k = 0; k < 4; ++k) {
    const int bt = tid + k * 256;
    if (bt < NBT) {
      const unsigned word = s_packed[bt];
      if (word & VALID_BIT) {
        const int b = bt / NT, t = bt - b * NT;
        const unsigned keymask = 0xFFFFu | (0x1Fu << 21);
        const unsigned mykey = word & keymask;
        bool winner = true;  // last-update-wins per (cell, best_n)
        for (int t2 = t + 1; t2 < NT; ++t2) {
          const unsigned w2 = s_packed[b * NT + t2];
          if ((w2 & VALID_BIT) && ((w2 & keymask) == mykey)) { winner = false; break; }
        }
        if (winner) {
          const int gi = word & 0xFF, gj = (word >> 8) & 0xFF;
          const int bestn = __ffs((word >> 21) & 0x1F) - 1;
          const float* tr = tgt + (size_t)bt * TCH;
          const float gx = tr[0] * 0.25f, gy = tr[1] * 0.25f;
          const float gh = tr[3] * 0.25f, gw = tr[4] * 0.25f;
          const float txv = atanhf(gx - ((float)gi + 0.5f));
          const float tyv = atanhf(gy - ((float)gj + 0.5f));
          const float twv = logf(gw / c_aw[bestn] + 1e-16f);
          const float thv = logf(gh / c_ah[bestn] + 1e-16f);
          float bc = tr[13]; int label = 0;
          for (int c = 1; c < NC; ++c)
            if (tr[13 + c] > bc) { bc = tr[13 + c]; label = c; }
          const float* p = pred + ((((size_t)b * NA + bestn) * NH + gj) * NW + gi) * CH;
          const float l0 = p[0];
          cx  += (p[1] - txv) * (p[1] - txv);
          cy  += (p[2] - tyv) * (p[2] - tyv);
          chh += (p[4] - thv) * (p[4] - thv);
          cw  += (p[5] - twv) * (p[5] - twv);
          float m = p[6];
          for (int c = 1; c < NC; ++c) m = fmaxf(m, p[6 + c]);
          float se = 0.f;
          for (int c = 0; c < NC; ++c) se += expf(p[6 + c] - m);
          cce += (m + logf(se)) - p[6 + label];
          cn += 1.f;
          const float b0 = bce0(l0);
          s_ob  += b0 - l0;   // bce(l,1) = bce(l,0) - l
          s_sub += b0;        // remove mask cell from noobj sum
          n_msk += 1.f;
        }
      }
    }
  }

  for (int off = 32; off >= 1; off >>= 1) {
    cx  += __shfl_down(cx, off, 64);   cy    += __shfl_down(cy, off, 64);
    cw  += __shfl_down(cw, off, 64);   chh   += __shfl_down(chh, off, 64);
    cce += __shfl_down(cce, off, 64);  cn    += __shfl_down(cn, off, 64);
    s_ob+= __shfl_down(s_ob, off, 64); s_sub += __shfl_down(s_sub, off, 64);
    n_msk += __shfl_down(n_msk, off, 64);
  }
  if ((tid & 63) == 0) {
    atomicAdd(&s_acc[0], cx);   atomicAdd(&s_acc[1], cy);
    atomicAdd(&s_acc[2], cw);   atomicAdd(&s_acc[3], chh);
    atomicAdd(&s_acc[4], cce);  atomicAdd(&s_acc[5], cn);
    atomicAdd(&s_acc[6], s_ob); atomicAdd(&s_acc[7], s_sub);
    atomicAdd(&s_acc[8], n_msk);
  }
  __syncthreads();
  if (tid < 9) acc[tid] = s_acc[tid];
}

__global__ __launch_bounds__(1024) void k_fin(
    const float* __restrict__ pred, const unsigned* __restrict__ packed,
    const float* __restrict__ acc, const float* __restrict__ partials,
    float* __restrict__ out) {
  __shared__ unsigned s_packed[NBT];
  __shared__ float sw[3][16];
  const int tid = threadIdx.x;
  if (tid < NBT) s_packed[tid] = packed[tid];
  float s_all = (tid < GBLK ? partials[tid] : 0.f) +
                (tid + 1024 < GBLK ? partials[tid + 1024] : 0.f);
  __syncthreads();

  // ignored-not-masked cells: first-wins dedupe per (cell, anchor), idempotent
  float s_ign = 0.f, n_ign = 0.f;
  for (int u = tid; u < NBT * NA; u += 1024) {
    const int bt = u / NA, a = u - bt * NA;
    const unsigned w = s_packed[bt];
    if (!(w & VALID_BIT) || !((w >> (16 + a)) & 1u)) continue;
    const int b = bt / NT, t = bt - b * NT;
    const unsigned key = w & 0xFFFFu;
    bool skip = false;
    for (int t2 = 0; t2 < t; ++t2) {   // earlier target already claims it
      const unsigned w2 = s_packed[b * NT + t2];
      if ((w2 & VALID_BIT) && ((w2 & 0xFFFFu) == key) && ((w2 >> (16 + a)) & 1u)) { skip = true; break; }
    }
    if (skip) continue;
    for (int t2 = 0; t2 < NT; ++t2) {  // masked by any target -> handled via mask path
      const unsigned w2 = s_packed[b * NT + t2];
      if ((w2 & VALID_BIT) && ((w2 & 0xFFFFu) == key) && ((w2 >> (21 + a)) & 1u)) { skip = true; break; }
    }
    if (skip) continue;
    const int gi = w & 0xFF, gj = (w >> 8) & 0xFF;
    s_ign += bce0(pred[((((size_t)b * NA + a) * NH + gj) * NW + gi) * CH]);
    n_ign += 1.f;
  }

  for (int off = 32; off >= 1; off >>= 1) {
    s_all += __shfl_down(s_all, off, 64);
    s_ign += __shfl_down(s_ign, off, 64);
    n_ign += __shfl_down(n_ign, off, 64);
  }
  const int wv = tid >> 6;
  if ((tid & 63) == 0) { sw[0][wv] = s_all; sw[1][wv] = s_ign; sw[2][wv] = n_ign; }
  __syncthreads();
  if (tid == 0) {
    float a0 = 0, a1 = 0, a2 = 0;
    for (int i = 0; i < 16; ++i) { a0 += sw[0][i]; a1 += sw[1][i]; a2 += sw[2][i]; }
    const float n_obj = fmaxf(acc[5], 1.f);
    const float n_noobj = fmaxf((float)NCELL - acc[8] - a2, 1.f);
    out[0] = (acc[0] + acc[1] + acc[2] + acc[3] + acc[4] + acc[6]) / n_obj +
             1.25f * (a0 - acc[7] - a1) / n_noobj;
  }
}

extern "C" void kernel_launch(void* const* d_in, const int* in_sizes, int n_in,
                              void* d_out, int out_size, void* d_ws, size_t ws_size,
                              hipStream_t stream) {
  const float* pred = (const float*)d_in[0];
  const float* tgt = (const float*)d_in[1];
  const int* tsz = (const int*)d_in[2];
  float* out = (float*)d_out;
  float* acc = (float*)d_ws;
  unsigned* packed = (unsigned*)((float*)d_ws + 64);
  float* partials = (float*)d_ws + 1024;

  k_main<<<GBLK + 1, 256, 0, stream>>>(pred, tgt, tsz, acc, packed, partials);
  k_fin<<<1, 1024, 0, stream>>>(pred, packed, acc, partials, out);
}

// Round 5
// 111.653 us; speedup vs baseline: 1.2435x; 1.0119x over previous
//
#include <hip/hip_runtime.h>
#include <cmath>

#define NB 16
#define NA 5
#define NH 152
#define NW 152
#define NT 50
#define NC 20
#define CH 26          // prediction channels
#define TCH 33         // target channels
#define NBT (NB * NT)  // 800 (b,t) pairs
#define NCELL (NB * NA * NH * NW)  // 1,848,320 conf cells
#define SBLK 3610      // stream blocks: 3610 * 3328 float4 == TOT4 exactly
#define BQ 3328        // float4 per stream block (= 13 * 256)

// anchors / SCALE
__device__ __constant__ float c_aw[NA] = {4.f, 8.f, 16.f, 24.f, 12.f};
__device__ __constant__ float c_ah[NA] = {4.f, 8.f, 16.f, 12.f, 24.f};

// packed word: bits0-7 gi | 8-15 gj | 16-20 ignore mask | 21-25 best_n one-hot | 26 valid
#define VALID_BIT (1u << 26)

__device__ __forceinline__ float bce0(float l) {  // bce(logit, target=0)
  return fmaxf(l, 0.f) + log1pf(expf(-fabsf(l)));
}

// ws float layout: [0..16) acc (0-3 coord, 4 ce, 5 n_obj, 6 s_ob, 7 s_sub_mask, 8 n_mask)
//                  [64..864)    packed words (800)
//                  [1024..4634) partials (3610, fully overwritten)

__global__ __launch_bounds__(256) void k_main(
    const float* __restrict__ pred, const float* __restrict__ tgt,
    const int* __restrict__ tsz, float* __restrict__ acc,
    unsigned* __restrict__ packed_out, float* __restrict__ partials) {
  if (blockIdx.x < SBLK) {
    // ---- coalesced full stream; conf extracted via residue tracking ----
    const float4* p4 = (const float4*)pred;
    const size_t base = (size_t)blockIdx.x * BQ + threadIdx.x;
    float4 v[13];
    #pragma unroll
    for (int k = 0; k < 13; ++k) v[k] = p4[base + (size_t)k * 256];
    // q_k = blk*3328 + k*256 + tid ; mod 13: 3328==0, 256==9 -> r_k = (tid + 9k) % 13
    int r = (int)(threadIdx.x % 13u);
    float c0 = 0.f, c6 = 0.f;  // each assigned exactly once over k=0..12
    #pragma unroll
    for (int k = 0; k < 13; ++k) {
      if (r == 0) c0 = v[k].x;        // float 4q     : channel 0
      else if (r == 6) c6 = v[k].z;   // float 4q + 2 : channel 0
      r += 9; if (r >= 13) r -= 13;
    }
    float s = bce0(c0) + bce0(c6);
    for (int off = 32; off >= 1; off >>= 1) s += __shfl_down(s, off, 64);
    __shared__ float sw[4];
    if ((threadIdx.x & 63) == 0) sw[threadIdx.x >> 6] = s;
    __syncthreads();
    if (threadIdx.x == 0) partials[blockIdx.x] = sw[0] + sw[1] + sw[2] + sw[3];
    return;
  }

  // ---- targets block (runs concurrently with the stream blocks) ----
  __shared__ unsigned s_packed[NBT];
  __shared__ float s_acc[9];
  const int tid = threadIdx.x;
  if (tid < 9) s_acc[tid] = 0.f;

  #pragma unroll
  for (int k = 0; k < 4; ++k) {
    const int bt = tid + k * 256;
    if (bt < NBT) {
      const int b = bt / NT, t = bt - b * NT;
      const float* tr = tgt + (size_t)bt * TCH;
      const float gx = tr[0] * 0.25f, gy = tr[1] * 0.25f;
      const float gh = tr[3] * 0.25f, gw = tr[4] * 0.25f;
      const bool valid = (t < tsz[b]) && (gw > 0.f) && (gh > 0.f);
      const int gi = min(max((int)gx, 0), NW - 1);
      const int gj = min(max((int)gy, 0), NH - 1);
      const float area_gt = (gw + 1.f) * (gh + 1.f);
      float best = -1.f; int bestn = 0; unsigned amask = 0;
      for (int a = 0; a < NA; ++a) {
        const float inter = (fminf(gw, c_aw[a]) + 1.f) * (fminf(gh, c_ah[a]) + 1.f);
        const float area_a = (c_aw[a] + 1.f) * (c_ah[a] + 1.f);
        const float iou = inter / (area_gt + area_a - inter + 1e-16f);
        if (iou > best) { best = iou; bestn = a; }   // first-max tie-break
        if (iou > 0.5f) amask |= (1u << a);
      }
      unsigned word = 0;
      if (valid)
        word = (unsigned)gi | ((unsigned)gj << 8) | (amask << 16) |
               (1u << (21 + bestn)) | VALID_BIT;
      s_packed[bt] = word;
      packed_out[bt] = word;
    }
  }
  __syncthreads();

  float cx = 0, cy = 0, cw = 0, chh = 0, cce = 0, cn = 0;
  float s_ob = 0, s_sub = 0, n_msk = 0;
  #pragma unroll
  for (int k = 0; k < 4; ++k) {
    const int bt = tid + k * 256;
    if (bt < NBT) {
      const unsigned word = s_packed[bt];
      if (word & VALID_BIT) {
        const int b = bt / NT, t = bt - b * NT;
        const unsigned keymask = 0xFFFFu | (0x1Fu << 21);
        const unsigned mykey = word & keymask;
        bool winner = true;  // last-update-wins per (cell, best_n)
        for (int t2 = t + 1; t2 < NT; ++t2) {
          const unsigned w2 = s_packed[b * NT + t2];
          if ((w2 & VALID_BIT) && ((w2 & keymask) == mykey)) { winner = false; break; }
        }
        if (winner) {
          const int gi = word & 0xFF, gj = (word >> 8) & 0xFF;
          const int bestn = __ffs((word >> 21) & 0x1F) - 1;
          const float* tr = tgt + (size_t)bt * TCH;
          const float gx = tr[0] * 0.25f, gy = tr[1] * 0.25f;
          const float gh = tr[3] * 0.25f, gw = tr[4] * 0.25f;
          const float txv = atanhf(gx - ((float)gi + 0.5f));
          const float tyv = atanhf(gy - ((float)gj + 0.5f));
          const float twv = logf(gw / c_aw[bestn] + 1e-16f);
          const float thv = logf(gh / c_ah[bestn] + 1e-16f);
          float bc = tr[13]; int label = 0;
          for (int c = 1; c < NC; ++c)
            if (tr[13 + c] > bc) { bc = tr[13 + c]; label = c; }
          const float* p = pred + ((((size_t)b * NA + bestn) * NH + gj) * NW + gi) * CH;
          const float l0 = p[0];
          cx  += (p[1] - txv) * (p[1] - txv);
          cy  += (p[2] - tyv) * (p[2] - tyv);
          chh += (p[4] - thv) * (p[4] - thv);
          cw  += (p[5] - twv) * (p[5] - twv);
          float m = p[6];
          for (int c = 1; c < NC; ++c) m = fmaxf(m, p[6 + c]);
          float se = 0.f;
          for (int c = 0; c < NC; ++c) se += expf(p[6 + c] - m);
          cce += (m + logf(se)) - p[6 + label];
          cn += 1.f;
          const float b0 = bce0(l0);
          s_ob  += b0 - l0;   // bce(l,1) = bce(l,0) - l
          s_sub += b0;        // remove mask cell from noobj sum
          n_msk += 1.f;
        }
      }
    }
  }

  for (int off = 32; off >= 1; off >>= 1) {
    cx  += __shfl_down(cx, off, 64);   cy    += __shfl_down(cy, off, 64);
    cw  += __shfl_down(cw, off, 64);   chh   += __shfl_down(chh, off, 64);
    cce += __shfl_down(cce, off, 64);  cn    += __shfl_down(cn, off, 64);
    s_ob+= __shfl_down(s_ob, off, 64); s_sub += __shfl_down(s_sub, off, 64);
    n_msk += __shfl_down(n_msk, off, 64);
  }
  if ((tid & 63) == 0) {
    atomicAdd(&s_acc[0], cx);   atomicAdd(&s_acc[1], cy);
    atomicAdd(&s_acc[2], cw);   atomicAdd(&s_acc[3], chh);
    atomicAdd(&s_acc[4], cce);  atomicAdd(&s_acc[5], cn);
    atomicAdd(&s_acc[6], s_ob); atomicAdd(&s_acc[7], s_sub);
    atomicAdd(&s_acc[8], n_msk);
  }
  __syncthreads();
  if (tid < 9) acc[tid] = s_acc[tid];
}

__global__ __launch_bounds__(1024) void k_fin(
    const float* __restrict__ pred, const unsigned* __restrict__ packed,
    const float* __restrict__ acc, const float* __restrict__ partials,
    float* __restrict__ out) {
  __shared__ unsigned s_packed[NBT];
  __shared__ float sw[3][16];
  const int tid = threadIdx.x;
  if (tid < NBT) s_packed[tid] = packed[tid];
  float s_all = 0.f;
  for (int i = tid; i < SBLK; i += 1024) s_all += partials[i];
  __syncthreads();

  // ignored-not-masked cells: first-wins dedupe per (cell, anchor), idempotent
  float s_ign = 0.f, n_ign = 0.f;
  for (int u = tid; u < NBT * NA; u += 1024) {
    const int bt = u / NA, a = u - bt * NA;
    const unsigned w = s_packed[bt];
    if (!(w & VALID_BIT) || !((w >> (16 + a)) & 1u)) continue;
    const int b = bt / NT, t = bt - b * NT;
    const unsigned key = w & 0xFFFFu;
    bool skip = false;
    for (int t2 = 0; t2 < t; ++t2) {   // earlier target already claims it
      const unsigned w2 = s_packed[b * NT + t2];
      if ((w2 & VALID_BIT) && ((w2 & 0xFFFFu) == key) && ((w2 >> (16 + a)) & 1u)) { skip = true; break; }
    }
    if (skip) continue;
    for (int t2 = 0; t2 < NT; ++t2) {  // masked by any target -> handled via mask path
      const unsigned w2 = s_packed[b * NT + t2];
      if ((w2 & VALID_BIT) && ((w2 & 0xFFFFu) == key) && ((w2 >> (21 + a)) & 1u)) { skip = true; break; }
    }
    if (skip) continue;
    const int gi = w & 0xFF, gj = (w >> 8) & 0xFF;
    s_ign += bce0(pred[((((size_t)b * NA + a) * NH + gj) * NW + gi) * CH]);
    n_ign += 1.f;
  }

  for (int off = 32; off >= 1; off >>= 1) {
    s_all += __shfl_down(s_all, off, 64);
    s_ign += __shfl_down(s_ign, off, 64);
    n_ign += __shfl_down(n_ign, off, 64);
  }
  const int wv = tid >> 6;
  if ((tid & 63) == 0) { sw[0][wv] = s_all; sw[1][wv] = s_ign; sw[2][wv] = n_ign; }
  __syncthreads();
  if (tid == 0) {
    float a0 = 0, a1 = 0, a2 = 0;
    for (int i = 0; i < 16; ++i) { a0 += sw[0][i]; a1 += sw[1][i]; a2 += sw[2][i]; }
    const float n_obj = fmaxf(acc[5], 1.f);
    const float n_noobj = fmaxf((float)NCELL - acc[8] - a2, 1.f);
    out[0] = (acc[0] + acc[1] + acc[2] + acc[3] + acc[4] + acc[6]) / n_obj +
             1.25f * (a0 - acc[7] - a1) / n_noobj;
  }
}

extern "C" void kernel_launch(void* const* d_in, const int* in_sizes, int n_in,
                              void* d_out, int out_size, void* d_ws, size_t ws_size,
                              hipStream_t stream) {
  const float* pred = (const float*)d_in[0];
  const float* tgt = (const float*)d_in[1];
  const int* tsz = (const int*)d_in[2];
  float* out = (float*)d_out;
  float* acc = (float*)d_ws;
  unsigned* packed = (unsigned*)((float*)d_ws + 64);
  float* partials = (float*)d_ws + 1024;

  k_main<<<SBLK + 1, 256, 0, stream>>>(pred, tgt, tsz, acc, packed, partials);
  k_fin<<<1, 1024, 0, stream>>>(pred, packed, acc, partials, out);
}

// Round 6
// 100.201 us; speedup vs baseline: 1.3856x; 1.1143x over previous
//
#include <hip/hip_runtime.h>
#include <cmath>

#define NB 16
#define NA 5
#define NH 152
#define NW 152
#define NT 50
#define NC 20
#define CH 26          // prediction channels
#define TCH 33         // target channels
#define NBT (NB * NT)  // 800 (b,t) pairs
#define NCELL (NB * NA * NH * NW)   // 1,848,320 conf cells
#define TOT4 12014080               // NCELL*26/4 float4 in pred
#define BQ 1024                     // float4 per stream block
#define NSB 11733                   // stream blocks (11732 full + 1 tail of 512)

// anchors / SCALE
__device__ __constant__ float c_aw[NA] = {4.f, 8.f, 16.f, 24.f, 12.f};
__device__ __constant__ float c_ah[NA] = {4.f, 8.f, 16.f, 12.f, 24.f};

// packed word: bits0-7 gi | 8-15 gj | 16-20 ignore mask | 21-25 best_n one-hot | 26 valid
#define VALID_BIT (1u << 26)

__device__ __forceinline__ float bce0(float l) {  // bce(logit, target=0), fast form
  const float e = exp2f(fabsf(l) * -1.4426950408889634f);
  return fmaxf(l, 0.f) + 0.69314718055994531f * log2f(1.f + e);
}

// ws float layout: [0..16) acc (0-3 coord, 4 ce, 5 n_obj, 6 s_ob, 7 s_sub_mask, 8 n_mask)
//                  [64..864)      packed words (800)
//                  [1024..12757)  partials (NSB, fully overwritten)

__global__ __launch_bounds__(256) void k_main(
    const float* __restrict__ pred, const float* __restrict__ tgt,
    const int* __restrict__ tsz, float* __restrict__ acc,
    unsigned* __restrict__ packed_out, float* __restrict__ partials) {
  const int tid = threadIdx.x;

  if (blockIdx.x != 0) {
    // ---------------- coalesced stream, 4 independent float4 loads ----------
    const int sb = blockIdx.x - 1;
    const float4* p4 = (const float4*)pred;
    const size_t base = (size_t)sb * BQ + tid;

    // residues: q = sb*1024 + k*256 + tid; 1024%13=10, 256%13=9
    // rbase = (10*sb + tid) % 13 ; rk = (rbase + (9k)%13) mod 13, offs = {0,9,5,1}
    const int rbase = (int)(((unsigned)(10 * sb) + (unsigned)tid) % 13u);

    float4 v0, v1, v2, v3;
    v2.x = v2.z = v3.x = v3.z = 0.f;
    const bool full = (sb != NSB - 1);   // tail block: only k=0,1 exist (512 = 2*256)
    v0 = p4[base];
    v1 = p4[base + 256];
    if (full) { v2 = p4[base + 512]; v3 = p4[base + 768]; }

    int r0 = rbase;               // + 0
    int r1 = rbase + 9;  r1 -= (r1 >= 13) ? 13 : 0;
    int r2 = rbase + 5;  r2 -= (r2 >= 13) ? 13 : 0;
    int r3 = rbase + 1;  r3 -= (r3 >= 13) ? 13 : 0;

    // branchless: pick candidate value, compute bce0 once, select-to-zero
    float s = 0.f;
    {
      const float val = (r0 == 0) ? v0.x : v0.z;
      const bool f = (r0 == 0) | (r0 == 6);
      s += f ? bce0(val) : 0.f;
    }
    {
      const float val = (r1 == 0) ? v1.x : v1.z;
      const bool f = (r1 == 0) | (r1 == 6);
      s += f ? bce0(val) : 0.f;
    }
    {
      const float val = (r2 == 0) ? v2.x : v2.z;
      const bool f = ((r2 == 0) | (r2 == 6)) && full;
      s += f ? bce0(val) : 0.f;
    }
    {
      const float val = (r3 == 0) ? v3.x : v3.z;
      const bool f = ((r3 == 0) | (r3 == 6)) && full;
      s += f ? bce0(val) : 0.f;
    }

    for (int off = 32; off >= 1; off >>= 1) s += __shfl_down(s, off, 64);
    __shared__ float sw[4];
    if ((tid & 63) == 0) sw[tid >> 6] = s;
    __syncthreads();
    if (tid == 0) partials[sb] = sw[0] + sw[1] + sw[2] + sw[3];
    return;
  }

  // ---------------- targets block (blockIdx 0, overlaps the stream) --------
  __shared__ unsigned s_packed[NBT];
  __shared__ float s_acc[9];
  if (tid < 9) s_acc[tid] = 0.f;

  #pragma unroll
  for (int k = 0; k < 4; ++k) {
    const int bt = tid + k * 256;
    if (bt < NBT) {
      const int b = bt / NT, t = bt - b * NT;
      const float* tr = tgt + (size_t)bt * TCH;
      const float gx = tr[0] * 0.25f, gy = tr[1] * 0.25f;
      const float gh = tr[3] * 0.25f, gw = tr[4] * 0.25f;
      const bool valid = (t < tsz[b]) && (gw > 0.f) && (gh > 0.f);
      const int gi = min(max((int)gx, 0), NW - 1);
      const int gj = min(max((int)gy, 0), NH - 1);
      const float area_gt = (gw + 1.f) * (gh + 1.f);
      float best = -1.f; int bestn = 0; unsigned amask = 0;
      for (int a = 0; a < NA; ++a) {
        const float inter = (fminf(gw, c_aw[a]) + 1.f) * (fminf(gh, c_ah[a]) + 1.f);
        const float area_a = (c_aw[a] + 1.f) * (c_ah[a] + 1.f);
        const float iou = inter / (area_gt + area_a - inter + 1e-16f);
        if (iou > best) { best = iou; bestn = a; }   // first-max tie-break
        if (iou > 0.5f) amask |= (1u << a);
      }
      unsigned word = 0;
      if (valid)
        word = (unsigned)gi | ((unsigned)gj << 8) | (amask << 16) |
               (1u << (21 + bestn)) | VALID_BIT;
      s_packed[bt] = word;
      packed_out[bt] = word;
    }
  }
  __syncthreads();

  float cx = 0, cy = 0, cw = 0, chh = 0, cce = 0, cn = 0;
  float s_ob = 0, s_sub = 0, n_msk = 0;
  #pragma unroll
  for (int k = 0; k < 4; ++k) {
    const int bt = tid + k * 256;
    if (bt < NBT) {
      const unsigned word = s_packed[bt];
      if (word & VALID_BIT) {
        const int b = bt / NT, t = bt - b * NT;
        const unsigned keymask = 0xFFFFu | (0x1Fu << 21);
        const unsigned mykey = word & keymask;
        bool winner = true;  // last-update-wins per (cell, best_n)
        for (int t2 = t + 1; t2 < NT; ++t2) {
          const unsigned w2 = s_packed[b * NT + t2];
          if ((w2 & VALID_BIT) && ((w2 & keymask) == mykey)) { winner = false; break; }
        }
        if (winner) {
          const int gi = word & 0xFF, gj = (word >> 8) & 0xFF;
          const int bestn = __ffs((word >> 21) & 0x1F) - 1;
          const float* tr = tgt + (size_t)bt * TCH;
          const float gx = tr[0] * 0.25f, gy = tr[1] * 0.25f;
          const float gh = tr[3] * 0.25f, gw = tr[4] * 0.25f;
          const float txv = atanhf(gx - ((float)gi + 0.5f));
          const float tyv = atanhf(gy - ((float)gj + 0.5f));
          const float twv = logf(gw / c_aw[bestn] + 1e-16f);
          const float thv = logf(gh / c_ah[bestn] + 1e-16f);
          float bc = tr[13]; int label = 0;
          for (int c = 1; c < NC; ++c)
            if (tr[13 + c] > bc) { bc = tr[13 + c]; label = c; }
          const float* p = pred + ((((size_t)b * NA + bestn) * NH + gj) * NW + gi) * CH;
          const float l0 = p[0];
          cx  += (p[1] - txv) * (p[1] - txv);
          cy  += (p[2] - tyv) * (p[2] - tyv);
          chh += (p[4] - thv) * (p[4] - thv);
          cw  += (p[5] - twv) * (p[5] - twv);
          float m = p[6];
          for (int c = 1; c < NC; ++c) m = fmaxf(m, p[6 + c]);
          float se = 0.f;
          for (int c = 0; c < NC; ++c) se += expf(p[6 + c] - m);
          cce += (m + logf(se)) - p[6 + label];
          cn += 1.f;
          const float b0 = bce0(l0);
          s_ob  += b0 - l0;   // bce(l,1) = bce(l,0) - l
          s_sub += b0;        // remove mask cell from noobj sum
          n_msk += 1.f;
        }
      }
    }
  }

  for (int off = 32; off >= 1; off >>= 1) {
    cx  += __shfl_down(cx, off, 64);   cy    += __shfl_down(cy, off, 64);
    cw  += __shfl_down(cw, off, 64);   chh   += __shfl_down(chh, off, 64);
    cce += __shfl_down(cce, off, 64);  cn    += __shfl_down(cn, off, 64);
    s_ob+= __shfl_down(s_ob, off, 64); s_sub += __shfl_down(s_sub, off, 64);
    n_msk += __shfl_down(n_msk, off, 64);
  }
  if ((tid & 63) == 0) {
    atomicAdd(&s_acc[0], cx);   atomicAdd(&s_acc[1], cy);
    atomicAdd(&s_acc[2], cw);   atomicAdd(&s_acc[3], chh);
    atomicAdd(&s_acc[4], cce);  atomicAdd(&s_acc[5], cn);
    atomicAdd(&s_acc[6], s_ob); atomicAdd(&s_acc[7], s_sub);
    atomicAdd(&s_acc[8], n_msk);
  }
  __syncthreads();
  if (tid < 9) acc[tid] = s_acc[tid];
}

__global__ __launch_bounds__(1024) void k_fin(
    const float* __restrict__ pred, const unsigned* __restrict__ packed,
    const float* __restrict__ acc, const float* __restrict__ partials,
    float* __restrict__ out) {
  __shared__ unsigned s_packed[NBT];
  __shared__ float sw[3][16];
  const int tid = threadIdx.x;
  if (tid < NBT) s_packed[tid] = packed[tid];
  float s_all = 0.f;
  for (int i = tid; i < NSB; i += 1024) s_all += partials[i];
  __syncthreads();

  // ignored-not-masked cells: first-wins dedupe per (cell, anchor), idempotent
  float s_ign = 0.f, n_ign = 0.f;
  for (int u = tid; u < NBT * NA; u += 1024) {
    const int bt = u / NA, a = u - bt * NA;
    const unsigned w = s_packed[bt];
    if (!(w & VALID_BIT) || !((w >> (16 + a)) & 1u)) continue;
    const int b = bt / NT, t = bt - b * NT;
    const unsigned key = w & 0xFFFFu;
    bool skip = false;
    for (int t2 = 0; t2 < t; ++t2) {   // earlier target already claims it
      const unsigned w2 = s_packed[b * NT + t2];
      if ((w2 & VALID_BIT) && ((w2 & 0xFFFFu) == key) && ((w2 >> (16 + a)) & 1u)) { skip = true; break; }
    }
    if (skip) continue;
    for (int t2 = 0; t2 < NT; ++t2) {  // masked by any target -> handled via mask path
      const unsigned w2 = s_packed[b * NT + t2];
      if ((w2 & VALID_BIT) && ((w2 & 0xFFFFu) == key) && ((w2 >> (21 + a)) & 1u)) { skip = true; break; }
    }
    if (skip) continue;
    const int gi = w & 0xFF, gj = (w >> 8) & 0xFF;
    s_ign += bce0(pred[((((size_t)b * NA + a) * NH + gj) * NW + gi) * CH]);
    n_ign += 1.f;
  }

  for (int off = 32; off >= 1; off >>= 1) {
    s_all += __shfl_down(s_all, off, 64);
    s_ign += __shfl_down(s_ign, off, 64);
    n_ign += __shfl_down(n_ign, off, 64);
  }
  const int wv = tid >> 6;
  if ((tid & 63) == 0) { sw[0][wv] = s_all; sw[1][wv] = s_ign; sw[2][wv] = n_ign; }
  __syncthreads();
  if (tid == 0) {
    float a0 = 0, a1 = 0, a2 = 0;
    for (int i = 0; i < 16; ++i) { a0 += sw[0][i]; a1 += sw[1][i]; a2 += sw[2][i]; }
    const float n_obj = fmaxf(acc[5], 1.f);
    const float n_noobj = fmaxf((float)NCELL - acc[8] - a2, 1.f);
    out[0] = (acc[0] + acc[1] + acc[2] + acc[3] + acc[4] + acc[6]) / n_obj +
             1.25f * (a0 - acc[7] - a1) / n_noobj;
  }
}

extern "C" void kernel_launch(void* const* d_in, const int* in_sizes, int n_in,
                              void* d_out, int out_size, void* d_ws, size_t ws_size,
                              hipStream_t stream) {
  const float* pred = (const float*)d_in[0];
  const float* tgt = (const float*)d_in[1];
  const int* tsz = (const int*)d_in[2];
  float* out = (float*)d_out;
  float* acc = (float*)d_ws;
  unsigned* packed = (unsigned*)((float*)d_ws + 64);
  float* partials = (float*)d_ws + 1024;

  k_main<<<NSB + 1, 256, 0, stream>>>(pred, tgt, tsz, acc, packed, partials);
  k_fin<<<1, 1024, 0, stream>>>(pred, packed, acc, partials, out);
}